// Round 1
// baseline (99.367 us; speedup 1.0000x reference)
//
#include <hip/hip_runtime.h>

#define NN    8192
#define INF_  256
#define OUTF  64
#define NH    2
#define NE    262144
#define CAP   256
#define NB    16
#define SLOPE 0.2f

// Detect whether edge_index was delivered as int64 (little-endian: every odd
// 32-bit word of the first 2048 is zero) or int32. Writes flag=1 for int64.
__global__ __launch_bounds__(1024) void detect_i64_kernel(const unsigned int* __restrict__ ei,
                                                          int* __restrict__ flag) {
  __shared__ int nz;
  if (threadIdx.x == 0) nz = 0;
  __syncthreads();
  if (ei[2u * threadIdx.x + 1u] != 0u) atomicAdd(&nz, 1);
  __syncthreads();
  if (threadIdx.x == 0) *flag = (nz == 0) ? 1 : 0;
}

// xh[h,n,o] = sum_k x[n,k] * W[h,k,o];  s1[h,n]=xh·a1[h];  s2[h,n]=xh·a2[h]
// block = 128 threads = (h,o); NB nodes per block staged in LDS.
__global__ __launch_bounds__(128) void xh_kernel(const float* __restrict__ x,
                                                 const float* __restrict__ W,
                                                 const float* __restrict__ a1,
                                                 const float* __restrict__ a2,
                                                 float* __restrict__ xh,
                                                 float* __restrict__ s1,
                                                 float* __restrict__ s2) {
  __shared__ float xs[NB][INF_];
  const int nb = blockIdx.x * NB;
  const int t  = threadIdx.x;
  const int h  = t >> 6, o = t & 63;
  {
    const float4* src = (const float4*)(x + (size_t)nb * INF_);
    float4* dst = (float4*)&xs[0][0];
    for (int idx = t; idx < NB * (INF_ / 4); idx += 128) dst[idx] = src[idx];
  }
  __syncthreads();
  float acc[NB];
#pragma unroll
  for (int i = 0; i < NB; ++i) acc[i] = 0.f;
  const float* Wc = W + (size_t)h * INF_ * OUTF + o;
#pragma unroll 4
  for (int k = 0; k < INF_; ++k) {
    const float wv = Wc[(size_t)k * OUTF];
#pragma unroll
    for (int i = 0; i < NB; ++i) acc[i] += xs[i][k] * wv;
  }
  const float a1v = a1[h * OUTF + o];
  const float a2v = a2[h * OUTF + o];
#pragma unroll
  for (int i = 0; i < NB; ++i) {
    const int n = nb + i;
    xh[((size_t)h * NN + n) * OUTF + o] = acc[i];
    float v1 = acc[i] * a1v;
    float v2 = acc[i] * a2v;
#pragma unroll
    for (int s = 32; s > 0; s >>= 1) {
      v1 += __shfl_xor(v1, s, 64);
      v2 += __shfl_xor(v2, s, 64);
    }
    if (o == 0) {
      s1[h * NN + n] = v1;
      s2[h * NN + n] = v2;
    }
  }
}

// Scatter edges into fixed-stride per-src rows (duplicates kept; dedup later).
__global__ __launch_bounds__(256) void edge_kernel(const int* __restrict__ ei,
                                                   const int* __restrict__ flag,
                                                   int* __restrict__ deg,
                                                   int* __restrict__ cols) {
  const int e = blockIdx.x * 256 + threadIdx.x;
  if (e >= NE) return;
  int i, j;
  if (*flag) {
    const long long* e64 = (const long long*)ei;
    i = (int)e64[e];
    j = (int)e64[NE + e];
  } else {
    i = ei[e];
    j = ei[NE + e];
  }
  const int pos = atomicAdd(&deg[i], 1);
  if (pos < CAP) cols[i * CAP + pos] = j;
}

// Block per src node i; wave 0 = head 0, wave 1 = head 1 (64 lanes = 64 feats).
__global__ __launch_bounds__(128) void agg_kernel(const float* __restrict__ xh,
                                                  const float* __restrict__ s1,
                                                  const float* __restrict__ s2,
                                                  const int* __restrict__ deg,
                                                  const int* __restrict__ cols,
                                                  float* __restrict__ out) {
  const int i = blockIdx.x;
  const int t = threadIdx.x;
  const int h = t >> 6, lane = t & 63;
  __shared__ int cj[CAP];
  __shared__ float wts[NH][CAP];
  int d = deg[i];
  if (d > CAP) d = CAP;
  for (int p = t; p < d; p += 128) cj[p] = cols[i * CAP + p];
  __syncthreads();
  // dedup: invalidate later occurrences of repeated dst (reference masks once)
  int clr[(CAP + 127) / 128];
  int nclr = 0;
  for (int p = t; p < d; p += 128) {
    const int v = cj[p];
    bool dup = false;
    for (int q = 0; q < p; ++q)
      if (cj[q] == v) { dup = true; break; }
    if (dup) clr[nclr++] = p;
  }
  __syncthreads();
  for (int c = 0; c < nclr; ++c) cj[clr[c]] = -1;
  __syncthreads();

  float out_v;
  if (d == 0) {
    // reference: all-NEG row -> uniform softmax over ALL nodes
    float acc = 0.f;
    const float* xhh = xh + (size_t)h * NN * OUTF + lane;
    for (int j = 0; j < NN; ++j) acc += xhh[(size_t)j * OUTF];
    out_v = acc * (1.f / (float)NN);
  } else {
    const float s1i = s1[h * NN + i];
    // phase 1: scores + row max
    float m = -1e30f;
    for (int p = lane; p < d; p += 64) {
      const int j = cj[p];
      float sc = -1e30f;
      if (j >= 0) {
        sc = s1i + s2[h * NN + j];
        sc = (sc >= 0.f) ? sc : SLOPE * sc;
      }
      wts[h][p] = sc;
      m = fmaxf(m, sc);
    }
#pragma unroll
    for (int s = 32; s > 0; s >>= 1) m = fmaxf(m, __shfl_xor(m, s, 64));
    // phase 2: exp + denom
    float dsum = 0.f;
    for (int p = lane; p < d; p += 64) {
      const float sc = wts[h][p];
      const float w = (sc > -1e29f) ? __expf(sc - m) : 0.f;
      wts[h][p] = w;
      dsum += w;
    }
#pragma unroll
    for (int s = 32; s > 0; s >>= 1) dsum += __shfl_xor(dsum, s, 64);
    __syncthreads();  // wts visible to all lanes (both heads hit this)
    // phase 3: weighted aggregation of xh rows
    const float inv = 1.f / dsum;
    float acc = 0.f;
    const float* xhh = xh + (size_t)h * NN * OUTF + lane;
    for (int p = 0; p < d; ++p) {
      const float w = wts[h][p];
      if (w > 0.f) {
        const int j = cj[p];
        acc += w * xhh[(size_t)j * OUTF];
      }
    }
    out_v = acc * inv;
  }
  out[(size_t)i * (NH * OUTF) + h * OUTF + lane] = out_v;
}

extern "C" void kernel_launch(void* const* d_in, const int* in_sizes, int n_in,
                              void* d_out, int out_size, void* d_ws, size_t ws_size,
                              hipStream_t stream) {
  const float* x  = (const float*)d_in[0];
  const int*   ei = (const int*)d_in[1];
  const float* W  = (const float*)d_in[2];
  const float* a1 = (const float*)d_in[3];
  const float* a2 = (const float*)d_in[4];
  float* out = (float*)d_out;

  char* ws = (char*)d_ws;
  float* xh  = (float*)(ws);                                   // 4 MB
  float* s1  = (float*)(ws + (4u << 20));                      // 64 KB
  float* s2  = (float*)(ws + (4u << 20) + (64u << 10));        // 64 KB
  int*   deg = (int*)  (ws + (4u << 20) + (128u << 10));       // 32 KB
  int*  cols = (int*)  (ws + (4u << 20) + (192u << 10));       // 8 MB
  int*  flag = (int*)  (ws + (4u << 20) + (192u << 10) + (size_t)NN * CAP * 4);

  hipMemsetAsync(deg, 0, NN * sizeof(int), stream);
  detect_i64_kernel<<<1, 1024, 0, stream>>>((const unsigned int*)ei, flag);
  xh_kernel<<<NN / NB, 128, 0, stream>>>(x, W, a1, a2, xh, s1, s2);
  edge_kernel<<<NE / 256, 256, 0, stream>>>(ei, flag, deg, cols);
  agg_kernel<<<NN, 128, 0, stream>>>(xh, s1, s2, deg, cols, out);
}

// Round 2
// 68.830 us; speedup vs baseline: 1.4437x; 1.4437x over previous
//
#include <hip/hip_runtime.h>

#define NN    8192
#define INF_  256
#define OUTF  64
#define NH    2
#define NE    262144
#define CAP   256
#define SLOPE 0.2f

typedef __attribute__((ext_vector_type(8))) short short8;
typedef __attribute__((ext_vector_type(4))) float f32x4;

__device__ __forceinline__ unsigned short f2bf(float f) {
  unsigned int u = __float_as_uint(f);
  u += 0x7fffu + ((u >> 16) & 1u);   // round-to-nearest-even
  return (unsigned short)(u >> 16);
}

// Detect int64-vs-int32 edge delivery AND zero the degree array (fused).
__global__ __launch_bounds__(1024) void detect_zero_kernel(const unsigned int* __restrict__ ei,
                                                           int* __restrict__ flag,
                                                           int* __restrict__ deg) {
  const int t = threadIdx.x;
  for (int i = t; i < NN; i += 1024) deg[i] = 0;
  __shared__ int nz;
  if (t == 0) nz = 0;
  __syncthreads();
  if (ei[2u * t + 1u] != 0u) atomicAdd(&nz, 1);
  __syncthreads();
  if (t == 0) *flag = (nz == 0) ? 1 : 0;
}

// Pack x -> bf16 [NN][256]; W -> Bt bf16 [128][256] (Bt[c][k] = W[c>>6][k][c&63]).
__global__ __launch_bounds__(256) void pack_kernel(const float* __restrict__ x,
                                                   const float* __restrict__ W,
                                                   unsigned short* __restrict__ xb,
                                                   unsigned short* __restrict__ Bt) {
  const int b = blockIdx.x, t = threadIdx.x;
  if (b < 2048) {
    const int idx = (b * 256 + t) * 4;
    const float4 v = *(const float4*)(x + idx);
    ushort4 o;
    o.x = f2bf(v.x); o.y = f2bf(v.y); o.z = f2bf(v.z); o.w = f2bf(v.w);
    *(ushort4*)(xb + idx) = o;
  } else {
    const int idx = (b - 2048) * 256 + t;      // 128 blocks * 256 = 32768
    const int c = idx >> 8, k = idx & 255;
    Bt[c * 256 + k] = f2bf(W[(c >> 6) * (INF_ * OUTF) + k * OUTF + (c & 63)]);
  }
}

// GEMM xh = x @ W  (M=8192, N=128=h*64+o, K=256) via bf16 MFMA; fused s1/s2
// epilogue from the f32 accumulator. One wave per 16 rows.
__global__ __launch_bounds__(64) void xh_mfma_kernel(const unsigned short* __restrict__ xb,
                                                     const unsigned short* __restrict__ Bt,
                                                     const float* __restrict__ a1,
                                                     const float* __restrict__ a2,
                                                     float* __restrict__ xh,
                                                     float* __restrict__ s1,
                                                     float* __restrict__ s2) {
  const int l = threadIdx.x;
  const int lo = l & 15, hi = l >> 4;
  const int n0 = blockIdx.x * 16;
  f32x4 acc[8] = {};
#pragma unroll
  for (int ks = 0; ks < 8; ++ks) {
    const short8 a = *(const short8*)(xb + (size_t)(n0 + lo) * INF_ + ks * 32 + hi * 8);
#pragma unroll
    for (int tc = 0; tc < 8; ++tc) {
      const short8 bf = *(const short8*)(Bt + (size_t)(tc * 16 + lo) * INF_ + ks * 32 + hi * 8);
      acc[tc] = __builtin_amdgcn_mfma_f32_16x16x32_bf16(a, bf, acc[tc], 0, 0, 0);
    }
  }
  // store xh[h][n][o]
#pragma unroll
  for (int tc = 0; tc < 8; ++tc) {
    const int h = tc >> 2;
    const int col = (tc * 16 + lo) & 63;
#pragma unroll
    for (int r = 0; r < 4; ++r) {
      const int row = n0 + hi * 4 + r;
      xh[((size_t)h * NN + row) * OUTF + col] = acc[tc][r];
    }
  }
  // s1[h][n] = xh[h][n][:].a1[h], s2 likewise — from f32 accumulator
  float a1c[8], a2c[8];
#pragma unroll
  for (int tc = 0; tc < 8; ++tc) {
    const int h = tc >> 2;
    const int col = (tc * 16 + lo) & 63;
    a1c[tc] = a1[h * OUTF + col];
    a2c[tc] = a2[h * OUTF + col];
  }
#pragma unroll
  for (int r = 0; r < 4; ++r) {
    float p10 = 0.f, p20 = 0.f, p11 = 0.f, p21 = 0.f;
#pragma unroll
    for (int tc = 0; tc < 4; ++tc) {
      p10 += acc[tc][r] * a1c[tc];
      p20 += acc[tc][r] * a2c[tc];
      p11 += acc[tc + 4][r] * a1c[tc + 4];
      p21 += acc[tc + 4][r] * a2c[tc + 4];
    }
#pragma unroll
    for (int s = 1; s < 16; s <<= 1) {
      p10 += __shfl_xor(p10, s, 64);
      p20 += __shfl_xor(p20, s, 64);
      p11 += __shfl_xor(p11, s, 64);
      p21 += __shfl_xor(p21, s, 64);
    }
    if (lo == 0) {
      const int row = n0 + hi * 4 + r;
      s1[row] = p10;  s1[NN + row] = p11;
      s2[row] = p20;  s2[NN + row] = p21;
    }
  }
}

// Scatter edges into fixed-stride per-src rows (duplicates kept; dedup in agg).
__global__ __launch_bounds__(256) void edge_kernel(const int* __restrict__ ei,
                                                   const int* __restrict__ flag,
                                                   int* __restrict__ deg,
                                                   int* __restrict__ cols) {
  const int e = blockIdx.x * 256 + threadIdx.x;
  if (e >= NE) return;
  int i, j;
  if (*flag) {
    const long long* e64 = (const long long*)ei;
    i = (int)e64[e];
    j = (int)e64[NE + e];
  } else {
    i = ei[e];
    j = ei[NE + e];
  }
  const int pos = atomicAdd(&deg[i], 1);
  if (pos < CAP) cols[i * CAP + pos] = j;
}

// Block (512 thr = 8 waves) per src node. wave w: h = w>>2, sub = w&3.
// O(d) bitmap dedup; waves 0/4 do softmax; gather split 4-ways per head.
__global__ __launch_bounds__(512) void agg_kernel(const float* __restrict__ xh,
                                                  const float* __restrict__ s1,
                                                  const float* __restrict__ s2,
                                                  const int* __restrict__ deg,
                                                  const int* __restrict__ cols,
                                                  float* __restrict__ out) {
  const int i = blockIdx.x;
  const int t = threadIdx.x;
  const int w = t >> 6, lane = t & 63;
  const int h = w >> 2, sub = w & 3;
  __shared__ int cj[CAP];
  __shared__ float wts[NH][CAP];
  __shared__ unsigned int bm[NN / 32];
  __shared__ float partial[8][OUTF];
  __shared__ float invs[NH];
  int d = deg[i];
  if (d > CAP) d = CAP;
  for (int p = t; p < d; p += 512) cj[p] = cols[i * CAP + p];
  for (int q = t; q < NN / 32; q += 512) bm[q] = 0u;
  __syncthreads();
  for (int p = t; p < d; p += 512) {
    const int j = cj[p];
    const unsigned int old = atomicOr(&bm[j >> 5], 1u << (j & 31));
    if ((old >> (j & 31)) & 1u) cj[p] = -1;   // duplicate (keep exactly one)
  }
  __syncthreads();

  float acc = 0.f;
  const float* xhh = xh + (size_t)h * NN * OUTF + lane;
  if (d == 0) {
    // reference: all-NEG row -> uniform softmax over ALL nodes
    for (int j = sub; j < NN; j += 4) acc += xhh[(size_t)j * OUTF];
    if (lane == 0 && sub == 0) invs[h] = 1.f / (float)NN;
  } else {
    if (sub == 0) {
      const float s1i = s1[h * NN + i];
      float m = -1e30f;
      for (int p = lane; p < d; p += 64) {
        const int j = cj[p];
        float sc = -1e30f;
        if (j >= 0) {
          sc = s1i + s2[h * NN + j];
          sc = (sc >= 0.f) ? sc : SLOPE * sc;
        }
        wts[h][p] = sc;
        m = fmaxf(m, sc);
      }
#pragma unroll
      for (int s = 32; s > 0; s >>= 1) m = fmaxf(m, __shfl_xor(m, s, 64));
      float ds = 0.f;
      for (int p = lane; p < d; p += 64) {
        const float sc = wts[h][p];
        const float wv = (sc > -1e29f) ? __expf(sc - m) : 0.f;
        wts[h][p] = wv;
        ds += wv;
      }
#pragma unroll
      for (int s = 32; s > 0; s >>= 1) ds += __shfl_xor(ds, s, 64);
      if (lane == 0) invs[h] = 1.f / ds;
    }
    __syncthreads();
    // branchless, 4-way-split gather
#pragma unroll 4
    for (int p = sub; p < d; p += 4) {
      const float wv = wts[h][p];
      int j = cj[p];
      j = (j < 0) ? 0 : j;          // wv==0 for dups, contributes nothing
      acc += wv * xhh[(size_t)j * OUTF];
    }
  }
  partial[w][lane] = acc;
  __syncthreads();
  if (t < 128) {
    const int h2 = t >> 6, lane2 = t & 63;
    const float v = (partial[h2 * 4 + 0][lane2] + partial[h2 * 4 + 1][lane2] +
                     partial[h2 * 4 + 2][lane2] + partial[h2 * 4 + 3][lane2]) * invs[h2];
    out[(size_t)i * (NH * OUTF) + h2 * OUTF + lane2] = v;
  }
}

extern "C" void kernel_launch(void* const* d_in, const int* in_sizes, int n_in,
                              void* d_out, int out_size, void* d_ws, size_t ws_size,
                              hipStream_t stream) {
  const float* x  = (const float*)d_in[0];
  const int*   ei = (const int*)d_in[1];
  const float* W  = (const float*)d_in[2];
  const float* a1 = (const float*)d_in[3];
  const float* a2 = (const float*)d_in[4];
  float* out = (float*)d_out;

  char* ws = (char*)d_ws;
  float*          xh  = (float*)(ws);                                    // 4 MB
  float*          s1  = (float*)(ws + (4u << 20));                       // 64 KB
  float*          s2  = (float*)(ws + (4u << 20) + (64u << 10));         // 64 KB
  int*            deg = (int*)  (ws + (4u << 20) + (128u << 10));        // 32 KB
  int*            cols= (int*)  (ws + (4u << 20) + (192u << 10));        // 8 MB
  unsigned short* xb  = (unsigned short*)(ws + (12u << 20) + (192u << 10)); // 4 MB
  unsigned short* Bt  = (unsigned short*)(ws + (16u << 20) + (192u << 10)); // 64 KB
  int*            flag= (int*)  (ws + (16u << 20) + (256u << 10));

  detect_zero_kernel<<<1, 1024, 0, stream>>>((const unsigned int*)ei, flag, deg);
  pack_kernel<<<2176, 256, 0, stream>>>(x, W, xb, Bt);
  xh_mfma_kernel<<<NN / 16, 64, 0, stream>>>(xb, Bt, a1, a2, xh, s1, s2);
  edge_kernel<<<NE / 256, 256, 0, stream>>>(ei, flag, deg, cols);
  agg_kernel<<<NN, 512, 0, stream>>>(xh, s1, s2, deg, cols, out);
}

// Round 3
// 55.031 us; speedup vs baseline: 1.8057x; 1.2508x over previous
//
#include <hip/hip_runtime.h>

#define NN    8192
#define INF_  256
#define OUTF  64
#define NH    2
#define NE    262144
#define CAP   256
#define SLOPE 0.2f

typedef __attribute__((ext_vector_type(8))) short short8;
typedef __attribute__((ext_vector_type(4))) float f32x4;

__device__ __forceinline__ unsigned short f2bf(float f) {
  unsigned int u = __float_as_uint(f);
  u += 0x7fffu + ((u >> 16) & 1u);   // round-to-nearest-even
  return (unsigned short)(u >> 16);
}

// One dispatch: blocks 0-127 pack W->Bt bf16; 128-159 zero deg; 160 detects
// int64-vs-int32 edge delivery (odd 32-bit words all zero => int64).
__global__ __launch_bounds__(256) void prep_kernel(const float* __restrict__ W,
                                                   const unsigned int* __restrict__ ei,
                                                   unsigned short* __restrict__ Bt,
                                                   int* __restrict__ deg,
                                                   int* __restrict__ flag) {
  const int b = blockIdx.x, t = threadIdx.x;
  if (b < 128) {
    const int c = b, k = t;
    Bt[c * 256 + k] = f2bf(W[(c >> 6) * (INF_ * OUTF) + k * OUTF + (c & 63)]);
  } else if (b < 160) {
    deg[(b - 128) * 256 + t] = 0;
  } else {
    __shared__ int nz;
    if (t == 0) nz = 0;
    __syncthreads();
    if (ei[2u * t + 1u] != 0u) atomicAdd(&nz, 1);
    __syncthreads();
    if (t == 0) *flag = (nz == 0) ? 1 : 0;
  }
}

// GEMM xh = x @ W (M=8192, N=128, K=256), bf16 MFMA, x converted in-register.
// 4 waves/block, 16 rows/wave. Fused s1/s2 epilogue from f32 accumulator.
__global__ __launch_bounds__(256) void xh_mfma_kernel(const float* __restrict__ x,
                                                      const unsigned short* __restrict__ Bt,
                                                      const float* __restrict__ a1,
                                                      const float* __restrict__ a2,
                                                      float* __restrict__ xh,
                                                      float* __restrict__ s1,
                                                      float* __restrict__ s2) {
  const int t = threadIdx.x;
  const int l = t & 63, wv = t >> 6;
  const int lo = l & 15, hi = l >> 4;
  const int n0 = (blockIdx.x * 4 + wv) * 16;
  f32x4 acc[8] = {};
  const float* xp = x + (size_t)(n0 + lo) * INF_ + hi * 8;
#pragma unroll
  for (int ks = 0; ks < 8; ++ks) {
    const float4 f0 = *(const float4*)(xp + ks * 32);
    const float4 f1 = *(const float4*)(xp + ks * 32 + 4);
    short8 a;
    a[0] = (short)f2bf(f0.x); a[1] = (short)f2bf(f0.y);
    a[2] = (short)f2bf(f0.z); a[3] = (short)f2bf(f0.w);
    a[4] = (short)f2bf(f1.x); a[5] = (short)f2bf(f1.y);
    a[6] = (short)f2bf(f1.z); a[7] = (short)f2bf(f1.w);
#pragma unroll
    for (int tc = 0; tc < 8; ++tc) {
      const short8 bf = *(const short8*)(Bt + (size_t)(tc * 16 + lo) * INF_ + ks * 32 + hi * 8);
      acc[tc] = __builtin_amdgcn_mfma_f32_16x16x32_bf16(a, bf, acc[tc], 0, 0, 0);
    }
  }
#pragma unroll
  for (int tc = 0; tc < 8; ++tc) {
    const int h = tc >> 2;
    const int col = (tc * 16 + lo) & 63;
#pragma unroll
    for (int r = 0; r < 4; ++r) {
      const int row = n0 + hi * 4 + r;
      xh[((size_t)h * NN + row) * OUTF + col] = acc[tc][r];
    }
  }
  float a1c[8], a2c[8];
#pragma unroll
  for (int tc = 0; tc < 8; ++tc) {
    const int h = tc >> 2;
    const int col = (tc * 16 + lo) & 63;
    a1c[tc] = a1[h * OUTF + col];
    a2c[tc] = a2[h * OUTF + col];
  }
#pragma unroll
  for (int r = 0; r < 4; ++r) {
    float p10 = 0.f, p20 = 0.f, p11 = 0.f, p21 = 0.f;
#pragma unroll
    for (int tc = 0; tc < 4; ++tc) {
      p10 += acc[tc][r] * a1c[tc];
      p20 += acc[tc][r] * a2c[tc];
      p11 += acc[tc + 4][r] * a1c[tc + 4];
      p21 += acc[tc + 4][r] * a2c[tc + 4];
    }
#pragma unroll
    for (int s = 1; s < 16; s <<= 1) {
      p10 += __shfl_xor(p10, s, 64);
      p20 += __shfl_xor(p20, s, 64);
      p11 += __shfl_xor(p11, s, 64);
      p21 += __shfl_xor(p21, s, 64);
    }
    if (lo == 0) {
      const int row = n0 + hi * 4 + r;
      s1[row] = p10;  s1[NN + row] = p11;
      s2[row] = p20;  s2[NN + row] = p21;
    }
  }
}

// Scatter edges into fixed-stride per-src rows (duplicates kept; dedup in agg).
__global__ __launch_bounds__(256) void edge_kernel(const int* __restrict__ ei,
                                                   const int* __restrict__ flag,
                                                   int* __restrict__ deg,
                                                   int* __restrict__ cols) {
  const int e = blockIdx.x * 256 + threadIdx.x;
  if (e >= NE) return;
  int i, j;
  if (*flag) {
    const long long* e64 = (const long long*)ei;
    i = (int)e64[e];
    j = (int)e64[NE + e];
  } else {
    i = ei[e];
    j = ei[NE + e];
  }
  const int pos = atomicAdd(&deg[i], 1);
  if (pos < CAP) cols[i * CAP + pos] = j;
}

// One block (128 thr = 2 waves, wave = head) per src node.
// Fast path d<=64: edge slot = lane; softmax entirely in registers; gather
// via dwordx4 with 4 rows/iter (row-slot r = lane>>4, feat-quad c4 = lane&15).
__global__ __launch_bounds__(128) void agg_kernel(const float* __restrict__ xh,
                                                  const float* __restrict__ s1,
                                                  const float* __restrict__ s2,
                                                  const int* __restrict__ deg,
                                                  const int* __restrict__ cols,
                                                  float* __restrict__ out) {
  const int i = blockIdx.x;
  const int t = threadIdx.x;
  const int h = t >> 6, lane = t & 63;
  __shared__ unsigned int bm[NN / 32];            // 1 KB dedup bitmap
  __shared__ unsigned long long vmask;
  __shared__ int   cjs[CAP];
  __shared__ float wts[NH][CAP];
  int d = deg[i];
  if (d > CAP) d = CAP;
  bm[t] = 0u; bm[t + 128] = 0u;
  __syncthreads();

  const float* base = xh + (size_t)h * NN * OUTF;
  const int c4 = lane & 15, r = lane >> 4;

  if (d == 0) {  // reference: all-NEG row -> uniform softmax over ALL nodes
    f32x4 acc = {0.f, 0.f, 0.f, 0.f};
    for (int p = r; p < NN; p += 4)
      acc += *(const f32x4*)(base + (size_t)p * OUTF + 4 * c4);
#pragma unroll
    for (int c = 0; c < 4; ++c) {
      acc[c] += __shfl_xor(acc[c], 16, 64);
      acc[c] += __shfl_xor(acc[c], 32, 64);
    }
    if (lane < 16) {
      const float sc = 1.f / (float)NN;
      float4 o;
      o.x = acc[0] * sc; o.y = acc[1] * sc; o.z = acc[2] * sc; o.w = acc[3] * sc;
      *(float4*)(out + (size_t)i * (NH * OUTF) + h * OUTF + 4 * lane) = o;
    }
    return;
  }

  if (d <= 64) {
    int j = 0;
    const bool valid = lane < d;
    if (valid) j = cols[i * CAP + lane];
    if (h == 0) {  // dedup once; head 1 reads the keep-mask
      bool dup = false;
      if (valid) {
        const unsigned int old = atomicOr(&bm[j >> 5], 1u << (j & 31));
        dup = (old >> (j & 31)) & 1u;
      }
      const unsigned long long bal = __ballot(valid && !dup);
      if (lane == 0) vmask = bal;
    }
    __syncthreads();
    const bool kp = (vmask >> lane) & 1ull;
    float sc = -1e30f;
    if (kp) {
      sc = s1[h * NN + i] + s2[h * NN + j];
      sc = (sc >= 0.f) ? sc : SLOPE * sc;
    }
    float m = sc;
#pragma unroll
    for (int s = 32; s > 0; s >>= 1) m = fmaxf(m, __shfl_xor(m, s, 64));
    const float wt = kp ? __expf(sc - m) : 0.f;
    float ds = wt;
#pragma unroll
    for (int s = 32; s > 0; s >>= 1) ds += __shfl_xor(ds, s, 64);
    const float inv = 1.f / ds;

    f32x4 acc = {0.f, 0.f, 0.f, 0.f};
#pragma unroll 2
    for (int p = 0; p < d; p += 4) {
      const int pr = p + r;
      float ww = __shfl(wt, pr, 64);
      int   jj = __shfl(j,  pr, 64);
      ww = (pr < d) ? ww : 0.f;
      jj = (ww > 0.f) ? jj : 0;
      const f32x4 v = *(const f32x4*)(base + (size_t)jj * OUTF + 4 * c4);
      acc += ww * v;
    }
#pragma unroll
    for (int c = 0; c < 4; ++c) {
      acc[c] += __shfl_xor(acc[c], 16, 64);
      acc[c] += __shfl_xor(acc[c], 32, 64);
    }
    if (lane < 16) {
      float4 o;
      o.x = acc[0] * inv; o.y = acc[1] * inv; o.z = acc[2] * inv; o.w = acc[3] * inv;
      *(float4*)(out + (size_t)i * (NH * OUTF) + h * OUTF + 4 * lane) = o;
    }
    return;
  }

  // slow path: 64 < d <= CAP (vanishingly rare at Poisson(32))
  for (int p = t; p < d; p += 128) cjs[p] = cols[i * CAP + p];
  __syncthreads();
  if (h == 0) {
    for (int p = lane; p < d; p += 64) {
      const int j = cjs[p];
      const unsigned int old = atomicOr(&bm[j >> 5], 1u << (j & 31));
      if ((old >> (j & 31)) & 1u) cjs[p] = -1;
    }
  }
  __syncthreads();
  const float s1i = s1[h * NN + i];
  float m = -1e30f;
  for (int p = lane; p < d; p += 64) {
    const int j = cjs[p];
    float sc = -1e30f;
    if (j >= 0) {
      sc = s1i + s2[h * NN + j];
      sc = (sc >= 0.f) ? sc : SLOPE * sc;
    }
    wts[h][p] = sc;
    m = fmaxf(m, sc);
  }
#pragma unroll
  for (int s = 32; s > 0; s >>= 1) m = fmaxf(m, __shfl_xor(m, s, 64));
  float ds = 0.f;
  for (int p = lane; p < d; p += 64) {
    const float sc = wts[h][p];
    const float w = (sc > -1e29f) ? __expf(sc - m) : 0.f;
    wts[h][p] = w;
    ds += w;
  }
#pragma unroll
  for (int s = 32; s > 0; s >>= 1) ds += __shfl_xor(ds, s, 64);
  const float inv = 1.f / ds;
  float acc = 0.f;
  for (int p = 0; p < d; ++p) {
    const float w = wts[h][p];
    if (w > 0.f) acc += w * base[(size_t)cjs[p] * OUTF + lane];
  }
  out[(size_t)i * (NH * OUTF) + h * OUTF + lane] = acc * inv;
}

extern "C" void kernel_launch(void* const* d_in, const int* in_sizes, int n_in,
                              void* d_out, int out_size, void* d_ws, size_t ws_size,
                              hipStream_t stream) {
  const float* x  = (const float*)d_in[0];
  const int*   ei = (const int*)d_in[1];
  const float* W  = (const float*)d_in[2];
  const float* a1 = (const float*)d_in[3];
  const float* a2 = (const float*)d_in[4];
  float* out = (float*)d_out;

  char* ws = (char*)d_ws;
  float*          xh  = (float*)(ws);                                 // 4 MB
  float*          s1  = (float*)(ws + (4u << 20));                    // 64 KB
  float*          s2  = (float*)(ws + (4u << 20) + (64u << 10));      // 64 KB
  int*            deg = (int*)  (ws + (4u << 20) + (128u << 10));     // 32 KB
  int*            cols= (int*)  (ws + (4u << 20) + (192u << 10));     // 8 MB
  unsigned short* Bt  = (unsigned short*)(ws + (12u << 20) + (192u << 10)); // 64 KB
  int*            flag= (int*)  (ws + (12u << 20) + (256u << 10));

  prep_kernel<<<161, 256, 0, stream>>>(W, (const unsigned int*)ei, Bt, deg, flag);
  xh_mfma_kernel<<<NN / 64, 256, 0, stream>>>(x, Bt, a1, a2, xh, s1, s2);
  edge_kernel<<<NE / 256, 256, 0, stream>>>(ei, flag, deg, cols);
  agg_kernel<<<NN, 128, 0, stream>>>(xh, s1, s2, deg, cols, out);
}

// Round 4
// 52.467 us; speedup vs baseline: 1.8939x; 1.0489x over previous
//
#include <hip/hip_runtime.h>

#define NN    8192
#define INF_  256
#define OUTF  64
#define NH    2
#define NE    262144
#define CAP   256
#define SLOPE 0.2f

typedef __attribute__((ext_vector_type(8))) short short8;
typedef __attribute__((ext_vector_type(4))) float f32x4;
typedef __attribute__((ext_vector_type(2))) long long ll2;

__device__ __forceinline__ unsigned short f2bf(float f) {
  unsigned int u = __float_as_uint(f);
  u += 0x7fffu + ((u >> 16) & 1u);   // round-to-nearest-even
  return (unsigned short)(u >> 16);
}

// One dispatch: blocks 0-127 pack W->Bt bf16; 128-159 zero deg; 160 detects
// int64-vs-int32 edge delivery (odd 32-bit words all zero => int64).
__global__ __launch_bounds__(256) void prep_kernel(const float* __restrict__ W,
                                                   const unsigned int* __restrict__ ei,
                                                   unsigned short* __restrict__ Bt,
                                                   int* __restrict__ deg,
                                                   int* __restrict__ flag) {
  const int b = blockIdx.x, t = threadIdx.x;
  if (b < 128) {
    const int c = b, k = t;
    Bt[c * 256 + k] = f2bf(W[(c >> 6) * (INF_ * OUTF) + k * OUTF + (c & 63)]);
  } else if (b < 160) {
    deg[(b - 128) * 256 + t] = 0;
  } else {
    __shared__ int nz;
    if (t == 0) nz = 0;
    __syncthreads();
    if (ei[2u * t + 1u] != 0u) atomicAdd(&nz, 1);
    __syncthreads();
    if (t == 0) *flag = (nz == 0) ? 1 : 0;
  }
}

// GEMM xh = x @ W (M=8192, N=128, K=256), bf16 MFMA.
// Block = 256 thr = 4 waves over ONE 16-row stripe; wave w owns col-tiles
// tc = {2w, 2w+1}. Grid 512 blocks -> 2048 waves (vs 512 before).
// All 16 x-loads hoisted to registers before conversion (one latency exposure).
__global__ __launch_bounds__(256) void xh_mfma_kernel(const float* __restrict__ x,
                                                      const unsigned short* __restrict__ Bt,
                                                      const float* __restrict__ a1,
                                                      const float* __restrict__ a2,
                                                      float* __restrict__ xh,
                                                      float* __restrict__ s1,
                                                      float* __restrict__ s2) {
  const int t = threadIdx.x;
  const int l = t & 63, w = t >> 6;
  const int lo = l & 15, hi = l >> 4;
  const int n0 = blockIdx.x * 16;
  const int tcb = w * 2;
  __shared__ float p1s[4][16], p2s[4][16];

  const float* xp = x + (size_t)(n0 + lo) * INF_ + hi * 8;
  float4 fr[16];
#pragma unroll
  for (int ks = 0; ks < 8; ++ks) {
    fr[2 * ks]     = *(const float4*)(xp + ks * 32);
    fr[2 * ks + 1] = *(const float4*)(xp + ks * 32 + 4);
  }
  short8 afr[8];
#pragma unroll
  for (int ks = 0; ks < 8; ++ks) {
    short8 a;
    a[0] = (short)f2bf(fr[2 * ks].x);     a[1] = (short)f2bf(fr[2 * ks].y);
    a[2] = (short)f2bf(fr[2 * ks].z);     a[3] = (short)f2bf(fr[2 * ks].w);
    a[4] = (short)f2bf(fr[2 * ks + 1].x); a[5] = (short)f2bf(fr[2 * ks + 1].y);
    a[6] = (short)f2bf(fr[2 * ks + 1].z); a[7] = (short)f2bf(fr[2 * ks + 1].w);
    afr[ks] = a;
  }
  f32x4 acc[2] = {};
#pragma unroll
  for (int ks = 0; ks < 8; ++ks) {
#pragma unroll
    for (int q = 0; q < 2; ++q) {
      const short8 bf = *(const short8*)(Bt + (size_t)((tcb + q) * 16 + lo) * INF_ + ks * 32 + hi * 8);
      acc[q] = __builtin_amdgcn_mfma_f32_16x16x32_bf16(afr[ks], bf, acc[q], 0, 0, 0);
    }
  }
  // store xh (C/D layout: col = lane&15 within tile, row = hi*4 + r)
  float a1c[2], a2c[2];
#pragma unroll
  for (int q = 0; q < 2; ++q) {
    const int tc = tcb + q;
    const int h = tc >> 2;
    const int col = (tc * 16 + lo) & 63;
    a1c[q] = a1[h * OUTF + col];
    a2c[q] = a2[h * OUTF + col];
#pragma unroll
    for (int r = 0; r < 4; ++r)
      xh[((size_t)h * NN + n0 + hi * 4 + r) * OUTF + col] = acc[q][r];
  }
  // s1/s2: per-wave partial dot over its 2 col-tiles, 16-lane reduce, LDS combine
#pragma unroll
  for (int r = 0; r < 4; ++r) {
    float p1 = acc[0][r] * a1c[0] + acc[1][r] * a1c[1];
    float p2 = acc[0][r] * a2c[0] + acc[1][r] * a2c[1];
#pragma unroll
    for (int s = 1; s < 16; s <<= 1) {
      p1 += __shfl_xor(p1, s, 64);
      p2 += __shfl_xor(p2, s, 64);
    }
    if (lo == 0) {
      p1s[w][hi * 4 + r] = p1;
      p2s[w][hi * 4 + r] = p2;
    }
  }
  __syncthreads();
  if (t < 16) {
    s1[n0 + t]      = p1s[0][t] + p1s[1][t];
    s1[NN + n0 + t] = p1s[2][t] + p1s[3][t];
    s2[n0 + t]      = p2s[0][t] + p2s[1][t];
    s2[NN + n0 + t] = p2s[2][t] + p2s[3][t];
  }
}

// Scatter edges into fixed-stride per-src rows; 2 edges per thread.
__global__ __launch_bounds__(256) void edge_kernel(const int* __restrict__ ei,
                                                   const int* __restrict__ flag,
                                                   int* __restrict__ deg,
                                                   int* __restrict__ cols) {
  const int e0 = (blockIdx.x * 256 + threadIdx.x) * 2;
  if (e0 >= NE) return;
  int i0, j0, i1, j1;
  if (*flag) {
    const ll2 a = *(const ll2*)((const long long*)ei + e0);
    const ll2 b = *(const ll2*)((const long long*)ei + NE + e0);
    i0 = (int)a[0]; i1 = (int)a[1]; j0 = (int)b[0]; j1 = (int)b[1];
  } else {
    const int2 a = *(const int2*)(ei + e0);
    const int2 b = *(const int2*)(ei + NE + e0);
    i0 = a.x; i1 = a.y; j0 = b.x; j1 = b.y;
  }
  const int p0 = atomicAdd(&deg[i0], 1);
  if (p0 < CAP) cols[i0 * CAP + p0] = j0;
  const int p1 = atomicAdd(&deg[i1], 1);
  if (p1 < CAP) cols[i1 * CAP + p1] = j1;
}

// One block (128 thr = 2 waves, wave = head) per src node.
// Fast path d<=64: edge slot = lane; softmax entirely in registers; gather
// via dwordx4 with 4 rows/iter (row-slot r = lane>>4, feat-quad c4 = lane&15).
__global__ __launch_bounds__(128) void agg_kernel(const float* __restrict__ xh,
                                                  const float* __restrict__ s1,
                                                  const float* __restrict__ s2,
                                                  const int* __restrict__ deg,
                                                  const int* __restrict__ cols,
                                                  float* __restrict__ out) {
  const int i = blockIdx.x;
  const int t = threadIdx.x;
  const int h = t >> 6, lane = t & 63;
  __shared__ unsigned int bm[NN / 32];            // 1 KB dedup bitmap
  __shared__ unsigned long long vmask;
  __shared__ int   cjs[CAP];
  __shared__ float wts[NH][CAP];
  int d = deg[i];
  if (d > CAP) d = CAP;
  bm[t] = 0u; bm[t + 128] = 0u;
  __syncthreads();

  const float* base = xh + (size_t)h * NN * OUTF;
  const int c4 = lane & 15, r = lane >> 4;

  if (d == 0) {  // reference: all-NEG row -> uniform softmax over ALL nodes
    f32x4 acc = {0.f, 0.f, 0.f, 0.f};
    for (int p = r; p < NN; p += 4)
      acc += *(const f32x4*)(base + (size_t)p * OUTF + 4 * c4);
#pragma unroll
    for (int c = 0; c < 4; ++c) {
      acc[c] += __shfl_xor(acc[c], 16, 64);
      acc[c] += __shfl_xor(acc[c], 32, 64);
    }
    if (lane < 16) {
      const float sc = 1.f / (float)NN;
      float4 o;
      o.x = acc[0] * sc; o.y = acc[1] * sc; o.z = acc[2] * sc; o.w = acc[3] * sc;
      *(float4*)(out + (size_t)i * (NH * OUTF) + h * OUTF + 4 * lane) = o;
    }
    return;
  }

  if (d <= 64) {
    int j = 0;
    const bool valid = lane < d;
    if (valid) j = cols[i * CAP + lane];
    if (h == 0) {  // dedup once; head 1 reads the keep-mask
      bool dup = false;
      if (valid) {
        const unsigned int old = atomicOr(&bm[j >> 5], 1u << (j & 31));
        dup = (old >> (j & 31)) & 1u;
      }
      const unsigned long long bal = __ballot(valid && !dup);
      if (lane == 0) vmask = bal;
    }
    __syncthreads();
    const bool kp = (vmask >> lane) & 1ull;
    float sc = -1e30f;
    if (kp) {
      sc = s1[h * NN + i] + s2[h * NN + j];
      sc = (sc >= 0.f) ? sc : SLOPE * sc;
    }
    float m = sc;
#pragma unroll
    for (int s = 32; s > 0; s >>= 1) m = fmaxf(m, __shfl_xor(m, s, 64));
    const float wt = kp ? __expf(sc - m) : 0.f;
    float ds = wt;
#pragma unroll
    for (int s = 32; s > 0; s >>= 1) ds += __shfl_xor(ds, s, 64);
    const float inv = 1.f / ds;

    f32x4 acc = {0.f, 0.f, 0.f, 0.f};
#pragma unroll 2
    for (int p = 0; p < d; p += 4) {
      const int pr = p + r;
      float ww = __shfl(wt, pr, 64);
      int   jj = __shfl(j,  pr, 64);
      ww = (pr < d) ? ww : 0.f;
      jj = (ww > 0.f) ? jj : 0;
      const f32x4 v = *(const f32x4*)(base + (size_t)jj * OUTF + 4 * c4);
      acc += ww * v;
    }
#pragma unroll
    for (int c = 0; c < 4; ++c) {
      acc[c] += __shfl_xor(acc[c], 16, 64);
      acc[c] += __shfl_xor(acc[c], 32, 64);
    }
    if (lane < 16) {
      float4 o;
      o.x = acc[0] * inv; o.y = acc[1] * inv; o.z = acc[2] * inv; o.w = acc[3] * inv;
      *(float4*)(out + (size_t)i * (NH * OUTF) + h * OUTF + 4 * lane) = o;
    }
    return;
  }

  // slow path: 64 < d <= CAP (vanishingly rare at Poisson(32))
  for (int p = t; p < d; p += 128) cjs[p] = cols[i * CAP + p];
  __syncthreads();
  if (h == 0) {
    for (int p = lane; p < d; p += 64) {
      const int j = cjs[p];
      const unsigned int old = atomicOr(&bm[j >> 5], 1u << (j & 31));
      if ((old >> (j & 31)) & 1u) cjs[p] = -1;
    }
  }
  __syncthreads();
  const float s1i = s1[h * NN + i];
  float m = -1e30f;
  for (int p = lane; p < d; p += 64) {
    const int j = cjs[p];
    float sc = -1e30f;
    if (j >= 0) {
      sc = s1i + s2[h * NN + j];
      sc = (sc >= 0.f) ? sc : SLOPE * sc;
    }
    wts[h][p] = sc;
    m = fmaxf(m, sc);
  }
#pragma unroll
  for (int s = 32; s > 0; s >>= 1) m = fmaxf(m, __shfl_xor(m, s, 64));
  float ds = 0.f;
  for (int p = lane; p < d; p += 64) {
    const float sc = wts[h][p];
    const float w2 = (sc > -1e29f) ? __expf(sc - m) : 0.f;
    wts[h][p] = w2;
    ds += w2;
  }
#pragma unroll
  for (int s = 32; s > 0; s >>= 1) ds += __shfl_xor(ds, s, 64);
  const float inv = 1.f / ds;
  float acc = 0.f;
  for (int p = 0; p < d; ++p) {
    const float w2 = wts[h][p];
    if (w2 > 0.f) acc += w2 * base[(size_t)cjs[p] * OUTF + lane];
  }
  out[(size_t)i * (NH * OUTF) + h * OUTF + lane] = acc * inv;
}

extern "C" void kernel_launch(void* const* d_in, const int* in_sizes, int n_in,
                              void* d_out, int out_size, void* d_ws, size_t ws_size,
                              hipStream_t stream) {
  const float* x  = (const float*)d_in[0];
  const int*   ei = (const int*)d_in[1];
  const float* W  = (const float*)d_in[2];
  const float* a1 = (const float*)d_in[3];
  const float* a2 = (const float*)d_in[4];
  float* out = (float*)d_out;

  char* ws = (char*)d_ws;
  float*          xh  = (float*)(ws);                                 // 4 MB
  float*          s1  = (float*)(ws + (4u << 20));                    // 64 KB
  float*          s2  = (float*)(ws + (4u << 20) + (64u << 10));      // 64 KB
  int*            deg = (int*)  (ws + (4u << 20) + (128u << 10));     // 32 KB
  int*            cols= (int*)  (ws + (4u << 20) + (192u << 10));     // 8 MB
  unsigned short* Bt  = (unsigned short*)(ws + (12u << 20) + (192u << 10)); // 64 KB
  int*            flag= (int*)  (ws + (12u << 20) + (256u << 10));

  prep_kernel<<<161, 256, 0, stream>>>(W, (const unsigned int*)ei, Bt, deg, flag);
  xh_mfma_kernel<<<NN / 16, 256, 0, stream>>>(x, Bt, a1, a2, xh, s1, s2);
  edge_kernel<<<NE / 512, 256, 0, stream>>>(ei, flag, deg, cols);
  agg_kernel<<<NN, 128, 0, stream>>>(xh, s1, s2, deg, cols, out);
}